// Round 6
// baseline (254.059 us; speedup 1.0000x reference)
//
#include <hip/hip_runtime.h>
#include <hip/hip_bf16.h>
#include <stdint.h>

#define B_ 4
#define M_ 1024
#define N_ 2048
#define D_ 1024
#define H_ 16
#define DH_ 64

typedef __bf16 bf16_t;
typedef __attribute__((ext_vector_type(8))) __bf16 bf16x8;
typedef __attribute__((ext_vector_type(4))) __bf16 bf16x4;
typedef __attribute__((ext_vector_type(4))) float f32x4;

static __device__ __forceinline__ float silu_f(float x) {
  return x / (1.0f + __expf(-x));
}

// Fused param-free cross-attention. One kernel, no workspace.
// grid 512 = mq(8) x bh(64); bx&63=bh so all m-blocks of one bh share an XCD.
// 256 threads = 4 waves x 32 Q-rows. Per 64-wide n-tile: stage K'(silu+norm,bf16)
// and V (bf16, swizzled [d][n]) in LDS, S^T = K'Q'^T via MFMA, fixed-max softmax
// (unit vectors -> |s|<=1, constant shift is exact), P^T through wave-private
// swizzled LDS (b64 writes / b128 reads), O^T += V^T P^T via MFMA.
__global__ __launch_bounds__(256, 2) void attn_fused(
    const float* __restrict__ q, const float* __restrict__ kv,
    const int* __restrict__ kv_mask, float* __restrict__ out) {
  __shared__ __align__(16) bf16_t Ks[64][72];        // K' [n][d], pitch 72
  __shared__ __align__(16) bf16_t Vs[4096];          // V [d][n] XOR-swizzled
  __shared__ __align__(16) bf16_t Pt[4][2][1024];    // per-wave per-mt P [m][n] swizzled

  const int tid = threadIdx.x;
  const int w = tid >> 6, lane = tid & 63;
  const int l15 = lane & 15, quad = lane >> 4;
  const int l7 = l15 & 7;
  const int bx = blockIdx.x;
  const int bh = bx & 63, mq = bx >> 6;
  const int b = bh >> 4, h = bh & 15;

  // staging assignment: row sr (0..63), col-quarter sp (16 floats each)
  const int sr = tid >> 2, sp = tid & 3;

  // ---- Q B-frags direct from global: rows m = mq*128 + w*32 + mt*16 + l15 ----
  bf16x8 qa[2][2];
  #pragma unroll
  for (int mt = 0; mt < 2; ++mt) {
    const float* qrow =
        q + ((size_t)(b * M_ + mq * 128 + w * 32 + mt * 16 + l15)) * D_ + h * DH_;
    float vals[16];
    float ss = 0.f;
    #pragma unroll
    for (int kc = 0; kc < 2; ++kc) {
      float4 a = *(const float4*)(qrow + kc * 32 + quad * 8);
      float4 c4 = *(const float4*)(qrow + kc * 32 + quad * 8 + 4);
      vals[kc * 8 + 0] = silu_f(a.x);  vals[kc * 8 + 1] = silu_f(a.y);
      vals[kc * 8 + 2] = silu_f(a.z);  vals[kc * 8 + 3] = silu_f(a.w);
      vals[kc * 8 + 4] = silu_f(c4.x); vals[kc * 8 + 5] = silu_f(c4.y);
      vals[kc * 8 + 6] = silu_f(c4.z); vals[kc * 8 + 7] = silu_f(c4.w);
    }
    #pragma unroll
    for (int i = 0; i < 16; ++i) ss += vals[i] * vals[i];
    ss += __shfl_xor(ss, 16); ss += __shfl_xor(ss, 32);
    const float inv = 1.0f / fmaxf(sqrtf(ss), 1e-6f);
    #pragma unroll
    for (int kc = 0; kc < 2; ++kc) {
      union { bf16_t b8[8]; bf16x8 v; } pq;
      #pragma unroll
      for (int i = 0; i < 8; ++i) pq.b8[i] = (bf16_t)(vals[kc * 8 + i] * inv);
      qa[mt][kc] = pq.v;
    }
  }

  f32x4 o[2][4];  // O^T accum: [mt][dt], row d = dt*16+quad*4+r, col m = mt*16+l15
  float lsum[2] = {0.f, 0.f};
  #pragma unroll
  for (int mt = 0; mt < 2; ++mt)
    #pragma unroll
    for (int dt = 0; dt < 4; ++dt) o[mt][dt] = (f32x4){0.f, 0.f, 0.f, 0.f};

  for (int t = 0; t < N_ / 64; ++t) {
    const int n0 = t * 64;
    // ---- stage: 16 floats per thread (row n0+sr, d = sp*16 .. +15) ----
    {
      const float* src = kv + ((size_t)(b * N_ + n0 + sr)) * D_ + h * DH_ + sp * 16;
      union { float f[16]; float4 v4[4]; } raw;
      raw.v4[0] = *(const float4*)(src + 0);
      raw.v4[1] = *(const float4*)(src + 4);
      raw.v4[2] = *(const float4*)(src + 8);
      raw.v4[3] = *(const float4*)(src + 12);
      float sv[16];
      float ss = 0.f;
      #pragma unroll
      for (int i = 0; i < 16; ++i) { sv[i] = silu_f(raw.f[i]); ss += sv[i] * sv[i]; }
      ss += __shfl_xor(ss, 1); ss += __shfl_xor(ss, 2);  // reduce over sp (4 lanes)
      const float inv = 1.0f / fmaxf(sqrtf(ss), 1e-6f);
      union { bf16_t bs[16]; uint4 u[2]; } pk;
      #pragma unroll
      for (int i = 0; i < 16; ++i) pk.bs[i] = (bf16_t)(sv[i] * inv);
      *(uint4*)&Ks[sr][sp * 16] = pk.u[0];
      *(uint4*)&Ks[sr][sp * 16 + 8] = pk.u[1];
      // V -> swizzled Vs[d][n]: phys = d*64 + ((n>>3)^(d&7))*8 + (n&7);
      // stagger i by 2*sp so banks tile across the wave.
      #pragma unroll
      for (int s16 = 0; s16 < 16; ++s16) {
        const int i = (s16 + 2 * sp) & 15;
        const int d = sp * 16 + i;
        Vs[d * 64 + (((sr >> 3) ^ (d & 7)) << 3) + (sr & 7)] = (bf16_t)raw.f[i];
      }
    }
    __syncthreads();

    const unsigned long long mk = __ballot(kv_mask[b * N_ + n0 + lane] != 0);

    // ---- S^T = K' Q'^T : C row n = 16j + quad*4 + r, col m = l15 ----
    f32x4 s[2][4];
    #pragma unroll
    for (int mt = 0; mt < 2; ++mt)
      #pragma unroll
      for (int j = 0; j < 4; ++j) s[mt][j] = (f32x4){0.f, 0.f, 0.f, 0.f};
    #pragma unroll
    for (int kc = 0; kc < 2; ++kc)
      #pragma unroll
      for (int j = 0; j < 4; ++j) {
        bf16x8 kbv = *(const bf16x8*)&Ks[j * 16 + l15][kc * 32 + quad * 8];
        s[0][j] = __builtin_amdgcn_mfma_f32_16x16x32_bf16(kbv, qa[0][kc], s[0][j], 0, 0, 0);
        s[1][j] = __builtin_amdgcn_mfma_f32_16x16x32_bf16(kbv, qa[1][kc], s[1][j], 0, 0, 0);
      }

    // ---- fixed-max softmax + P^T -> wave-private swizzled LDS ----
    #pragma unroll
    for (int mt = 0; mt < 2; ++mt) {
      #pragma unroll
      for (int j = 0; j < 4; ++j) {
        union { bf16_t b4[4]; bf16x4 v; } pp;
        #pragma unroll
        for (int r = 0; r < 4; ++r) {
          const int n = 16 * j + quad * 4 + r;
          const float p = ((mk >> n) & 1ull)
                              ? 0.f
                              : __expf(s[mt][j][r] * 0.125f - 0.125f);
          lsum[mt] += p;
          pp.b4[r] = (bf16_t)p;
        }
        const int gs = (2 * j + (quad >> 1)) ^ l7;
        *(bf16x4*)&Pt[w][mt][l15 * 64 + gs * 8 + (quad & 1) * 4] = pp.v;
      }
    }

    // ---- O^T += V^T P^T ----
    #pragma unroll
    for (int kk = 0; kk < 2; ++kk) {
      bf16x8 pf0 = *(const bf16x8*)&Pt[w][0][l15 * 64 + (((kk * 4 + quad) ^ l7) << 3)];
      bf16x8 pf1 = *(const bf16x8*)&Pt[w][1][l15 * 64 + (((kk * 4 + quad) ^ l7) << 3)];
      #pragma unroll
      for (int dt = 0; dt < 4; ++dt) {
        const int d = dt * 16 + l15;
        bf16x8 vbv = *(const bf16x8*)&Vs[d * 64 + (((kk * 4 + quad) ^ (d & 7)) << 3)];
        o[0][dt] = __builtin_amdgcn_mfma_f32_16x16x32_bf16(vbv, pf0, o[0][dt], 0, 0, 0);
        o[1][dt] = __builtin_amdgcn_mfma_f32_16x16x32_bf16(vbv, pf1, o[1][dt], 0, 0, 0);
      }
    }
    __syncthreads();  // protect Ks/Vs before next staging
  }

  // ---- epilogue: l lives on col m=l15 lanes; contiguous float4 stores ----
  #pragma unroll
  for (int mt = 0; mt < 2; ++mt) {
    lsum[mt] += __shfl_xor(lsum[mt], 16);
    lsum[mt] += __shfl_xor(lsum[mt], 32);
    const float invl = lsum[mt] > 0.f ? 1.0f / lsum[mt] : 0.f;
    const size_t rowbase =
        ((size_t)(b * M_ + mq * 128 + w * 32 + mt * 16 + l15)) * D_ + h * DH_;
    #pragma unroll
    for (int dt = 0; dt < 4; ++dt) {
      float4 st = {o[mt][dt][0] * invl, o[mt][dt][1] * invl,
                   o[mt][dt][2] * invl, o[mt][dt][3] * invl};
      *(float4*)(out + rowbase + dt * 16 + quad * 4) = st;
    }
  }
}

extern "C" void kernel_launch(void* const* d_in, const int* in_sizes, int n_in,
                              void* d_out, int out_size, void* d_ws, size_t ws_size,
                              hipStream_t stream) {
  const float* q = (const float*)d_in[0];
  const float* kv = (const float*)d_in[1];
  const int* kv_mask = (const int*)d_in[2];
  float* out = (float*)d_out;
  (void)d_ws; (void)ws_size;

  attn_fused<<<512, 256, 0, stream>>>(q, kv, kv_mask, out);
}

// Round 7
// 173.164 us; speedup vs baseline: 1.4672x; 1.4672x over previous
//
#include <hip/hip_runtime.h>
#include <hip/hip_bf16.h>
#include <stdint.h>

#define B_ 4
#define M_ 1024
#define N_ 2048
#define D_ 1024
#define H_ 16
#define DH_ 64

typedef __bf16 bf16_t;
typedef __attribute__((ext_vector_type(8))) __bf16 bf16x8;
typedef __attribute__((ext_vector_type(4))) __bf16 bf16x4;
typedef __attribute__((ext_vector_type(4))) float f32x4;

#define LOG2E 1.44269504088896340736f

static __device__ __forceinline__ float silu_f(float x) {
  // x * 1/(1+exp(-x)); exp via exp2, division via fast rcp (~1ulp, ok for bf16)
  const float e = __builtin_exp2f(-x * LOG2E);
  return x * __builtin_amdgcn_rcpf(1.0f + e);
}

// ---- prep (fused): reads kv once; writes K'=L2norm(silu(heads)) -> kp[bh][n][d]
//      and V^T (raw bf16) -> vt[bh][d][n]. grid b(4) x nt(8x256rows) x h(16) = 512.
__global__ __launch_bounds__(256) void prep_kernel(
    const float* __restrict__ kv, bf16_t* __restrict__ kp,
    bf16_t* __restrict__ vt) {
  __shared__ __align__(16) bf16_t Vt2[256][68];
  const int bx = blockIdx.x;
  const int h = bx & 15, nt = (bx >> 4) & 7, b = bx >> 7;
  const int n0 = nt * 256;
  const int tid = threadIdx.x;
  const size_t bh = (size_t)(b * H_ + h);
  #pragma unroll
  for (int it = 0; it < 16; ++it) {
    const int r = it * 16 + (tid >> 4);
    const int c = (tid & 15) * 4;
    float4 v = *(const float4*)(kv + ((size_t)(b * N_ + n0 + r)) * D_ + h * DH_ + c);
    // silu + row L2-norm (16 lanes per row)
    float s0 = silu_f(v.x), s1 = silu_f(v.y), s2 = silu_f(v.z), s3 = silu_f(v.w);
    float ss = s0 * s0 + s1 * s1 + s2 * s2 + s3 * s3;
    ss += __shfl_xor(ss, 1); ss += __shfl_xor(ss, 2);
    ss += __shfl_xor(ss, 4); ss += __shfl_xor(ss, 8);
    const float inv = 1.0f / fmaxf(sqrtf(ss), 1e-6f);
    union { bf16_t b4[4]; uint2 u; } pk;
    pk.b4[0] = (bf16_t)(s0 * inv); pk.b4[1] = (bf16_t)(s1 * inv);
    pk.b4[2] = (bf16_t)(s2 * inv); pk.b4[3] = (bf16_t)(s3 * inv);
    *(uint2*)(kp + (bh * N_ + n0 + r) * DH_ + c) = pk.u;
    // raw V bf16 -> LDS tile for transpose
    union { bf16_t b4[4]; uint2 u; } pv;
    pv.b4[0] = (bf16_t)v.x; pv.b4[1] = (bf16_t)v.y;
    pv.b4[2] = (bf16_t)v.z; pv.b4[3] = (bf16_t)v.w;
    *(uint2*)&Vt2[r][c] = pv.u;
  }
  __syncthreads();
  #pragma unroll
  for (int pass = 0; pass < 4; ++pass) {
    const int d = pass * 16 + (tid >> 4);
    const int nst = (tid & 15) * 16;
    union { bf16_t bs[16]; uint4 u[2]; } pk;
    #pragma unroll
    for (int kk = 0; kk < 16; ++kk) pk.bs[kk] = Vt2[nst + kk][d];
    uint4* dst = (uint4*)(vt + (bh * DH_ + d) * N_ + n0 + nst);
    dst[0] = pk.u[0]; dst[1] = pk.u[1];
  }
}

// ---- attn: flash cross-attention. BM=128 (4 waves x 32 rows), NT=64.
//      b128 staging of preprocessed bf16 tiles; S^T = K'Q'^T; fixed-max softmax;
//      P^T via wave-private swizzled LDS (b64 w / b128 r); O^T += V^T P^T.
//      grid 512 = mq(8) x bh(64); bx&63=bh -> bh's kv slice stays in one XCD L2.
__global__ __launch_bounds__(256, 2) void attn_kernel(
    const float* __restrict__ q, const bf16_t* __restrict__ kp,
    const bf16_t* __restrict__ vt, const int* __restrict__ kv_mask,
    float* __restrict__ out) {
  __shared__ __align__(16) bf16_t Ks[64][72];      // K' [n][d]
  __shared__ __align__(16) bf16_t Vs[64][72];      // V^T [d][n]
  __shared__ __align__(16) bf16_t Pt[4][2][1024];  // per-wave per-mt P, swizzled

  const int tid = threadIdx.x;
  const int w = tid >> 6, lane = tid & 63;
  const int l15 = lane & 15, quad = lane >> 4;
  const int l7 = l15 & 7;
  const int bx = blockIdx.x;
  const int bh = bx & 63, mq = bx >> 6;
  const int b = bh >> 4, h = bh & 15;

  // ---- Q B-frags from global: rows m = mq*128 + w*32 + mt*16 + l15 ----
  bf16x8 qa[2][2];
  #pragma unroll
  for (int mt = 0; mt < 2; ++mt) {
    const float* qrow =
        q + ((size_t)(b * M_ + mq * 128 + w * 32 + mt * 16 + l15)) * D_ + h * DH_;
    float vals[16];
    float ss = 0.f;
    #pragma unroll
    for (int kc = 0; kc < 2; ++kc) {
      float4 a = *(const float4*)(qrow + kc * 32 + quad * 8);
      float4 c4 = *(const float4*)(qrow + kc * 32 + quad * 8 + 4);
      vals[kc * 8 + 0] = silu_f(a.x);  vals[kc * 8 + 1] = silu_f(a.y);
      vals[kc * 8 + 2] = silu_f(a.z);  vals[kc * 8 + 3] = silu_f(a.w);
      vals[kc * 8 + 4] = silu_f(c4.x); vals[kc * 8 + 5] = silu_f(c4.y);
      vals[kc * 8 + 6] = silu_f(c4.z); vals[kc * 8 + 7] = silu_f(c4.w);
    }
    #pragma unroll
    for (int i = 0; i < 16; ++i) ss += vals[i] * vals[i];
    ss += __shfl_xor(ss, 16); ss += __shfl_xor(ss, 32);
    const float inv = 1.0f / fmaxf(sqrtf(ss), 1e-6f);
    #pragma unroll
    for (int kc = 0; kc < 2; ++kc) {
      union { bf16_t b8[8]; bf16x8 v; } pq;
      #pragma unroll
      for (int i = 0; i < 8; ++i) pq.b8[i] = (bf16_t)(vals[kc * 8 + i] * inv);
      qa[mt][kc] = pq.v;
    }
  }

  f32x4 o[2][4];  // O^T: [mt][dt], row d = dt*16+quad*4+r, col m = mt*16+l15
  float lsum[2] = {0.f, 0.f};
  #pragma unroll
  for (int mt = 0; mt < 2; ++mt)
    #pragma unroll
    for (int dt = 0; dt < 4; ++dt) o[mt][dt] = (f32x4){0.f, 0.f, 0.f, 0.f};

  const bf16_t* kpb = kp + (size_t)bh * N_ * DH_;
  const bf16_t* vtb = vt + (size_t)bh * DH_ * N_;
  const int* mkb = kv_mask + b * N_;

  for (int t = 0; t < N_ / 64; ++t) {
    const int n0 = t * 64;
    // ---- stage K'/V^T tiles: 2x bf16x8 per thread per array, b128 writes ----
    #pragma unroll
    for (int it = 0; it < 2; ++it) {
      const int slot = tid + it * 256;
      const int rr = slot >> 3, c8 = slot & 7;
      *(bf16x8*)&Ks[rr][c8 * 8] =
          *(const bf16x8*)(kpb + (size_t)(n0 + rr) * DH_ + c8 * 8);
      *(bf16x8*)&Vs[rr][c8 * 8] =
          *(const bf16x8*)(vtb + (size_t)rr * N_ + n0 + c8 * 8);
    }
    __syncthreads();

    const unsigned long long mk = __ballot(mkb[n0 + lane] != 0);

    // ---- S^T = K' Q'^T : C row n = 16j + quad*4 + r, col m = l15 ----
    f32x4 s[2][4];
    #pragma unroll
    for (int mt = 0; mt < 2; ++mt)
      #pragma unroll
      for (int j = 0; j < 4; ++j) s[mt][j] = (f32x4){0.f, 0.f, 0.f, 0.f};
    #pragma unroll
    for (int kc = 0; kc < 2; ++kc)
      #pragma unroll
      for (int j = 0; j < 4; ++j) {
        bf16x8 kbv = *(const bf16x8*)&Ks[j * 16 + l15][kc * 32 + quad * 8];
        s[0][j] = __builtin_amdgcn_mfma_f32_16x16x32_bf16(kbv, qa[0][kc], s[0][j], 0, 0, 0);
        s[1][j] = __builtin_amdgcn_mfma_f32_16x16x32_bf16(kbv, qa[1][kc], s[1][j], 0, 0, 0);
      }

    // ---- fixed-max softmax (|s|<=1): p = exp2(s*C - C), C = log2e/8 ----
    const float C = 0.125f * LOG2E;
    #pragma unroll
    for (int mt = 0; mt < 2; ++mt) {
      #pragma unroll
      for (int j = 0; j < 4; ++j) {
        union { bf16_t b4[4]; bf16x4 v; } pp;
        #pragma unroll
        for (int r = 0; r < 4; ++r) {
          const int n = 16 * j + quad * 4 + r;
          const float p = ((mk >> n) & 1ull)
                              ? 0.f
                              : __builtin_exp2f(s[mt][j][r] * C - C);
          lsum[mt] += p;
          pp.b4[r] = (bf16_t)p;
        }
        const int gs = (2 * j + (quad >> 1)) ^ l7;
        *(bf16x4*)&Pt[w][mt][l15 * 64 + gs * 8 + (quad & 1) * 4] = pp.v;
      }
    }

    // ---- O^T += V^T P^T ----
    #pragma unroll
    for (int kk = 0; kk < 2; ++kk) {
      bf16x8 pf0 = *(const bf16x8*)&Pt[w][0][l15 * 64 + (((kk * 4 + quad) ^ l7) << 3)];
      bf16x8 pf1 = *(const bf16x8*)&Pt[w][1][l15 * 64 + (((kk * 4 + quad) ^ l7) << 3)];
      #pragma unroll
      for (int dt = 0; dt < 4; ++dt) {
        bf16x8 vbv = *(const bf16x8*)&Vs[dt * 16 + l15][kk * 32 + quad * 8];
        o[0][dt] = __builtin_amdgcn_mfma_f32_16x16x32_bf16(vbv, pf0, o[0][dt], 0, 0, 0);
        o[1][dt] = __builtin_amdgcn_mfma_f32_16x16x32_bf16(vbv, pf1, o[1][dt], 0, 0, 0);
      }
    }
    __syncthreads();  // protect Ks/Vs before next staging
  }

  // ---- epilogue: l on col m=l15 lanes matches O^T cols; float4 stores ----
  #pragma unroll
  for (int mt = 0; mt < 2; ++mt) {
    lsum[mt] += __shfl_xor(lsum[mt], 16);
    lsum[mt] += __shfl_xor(lsum[mt], 32);
    const float invl = lsum[mt] > 0.f ? 1.0f / lsum[mt] : 0.f;
    const size_t rowbase =
        ((size_t)(b * M_ + mq * 128 + w * 32 + mt * 16 + l15)) * D_ + h * DH_;
    #pragma unroll
    for (int dt = 0; dt < 4; ++dt) {
      float4 st = {o[mt][dt][0] * invl, o[mt][dt][1] * invl,
                   o[mt][dt][2] * invl, o[mt][dt][3] * invl};
      *(float4*)(out + rowbase + dt * 16 + quad * 4) = st;
    }
  }
}

extern "C" void kernel_launch(void* const* d_in, const int* in_sizes, int n_in,
                              void* d_out, int out_size, void* d_ws, size_t ws_size,
                              hipStream_t stream) {
  const float* q = (const float*)d_in[0];
  const float* kv = (const float*)d_in[1];
  const int* kv_mask = (const int*)d_in[2];
  float* out = (float*)d_out;

  // ws: kp 16MB | vt 16MB
  const size_t kp_sz = (size_t)B_ * H_ * N_ * DH_ * sizeof(bf16_t);
  bf16_t* kp = (bf16_t*)d_ws;
  bf16_t* vt = (bf16_t*)((char*)d_ws + kp_sz);

  prep_kernel<<<512, 256, 0, stream>>>(kv, kp, vt);
  attn_kernel<<<512, 256, 0, stream>>>(q, kp, vt, kv_mask, out);
}